// Round 8
// baseline (152.029 us; speedup 1.0000x reference)
//
#include <hip/hip_runtime.h>

typedef _Float16 half8 __attribute__((ext_vector_type(8)));
typedef float f32x16 __attribute__((ext_vector_type(16)));

#define WD 7
#define NPAD 128
#define KDIM 8330
#define KT 8704          // 8 * KSLICE; wt rows zero-padded past 8330
#define BSZ 4096
#define SPLITK 8
#define KSLICE 1088      // 34 * 32
#define NITER 34
#define BK 32

// ws layout (bytes)
static constexpr size_t OFF_WT   = 0;                              // _Float16[2][128][KT]
static constexpr size_t WT_BYTES = (size_t)2 * NPAD * KT * 2;      // 4,456,448
static constexpr size_t OFF_BIAS = WT_BYTES;                       // 128 floats
static constexpr size_t OFF_PART = OFF_BIAS + 512;                 // [SPLITK][BSZ][NPAD] f32
// total ~21.2 MB

static __device__ const int KIDX[5][4] = {
    {0, 1, 3, 4}, {7, 8, 9, 10}, {5, 6, 11, 12}, {11, 12, 13, 14}, {15, 16, 15, 16}};
static __device__ const unsigned long long OBASE[5] = {0ull, 401408ull, 802816ull, 1204224ull, 1605632ull};

__device__ __forceinline__ unsigned pk16(_Float16 a, _Float16 b) {
  return (unsigned)__builtin_bit_cast(unsigned short, a) |
         ((unsigned)__builtin_bit_cast(unsigned short, b) << 16);
}

// ---------------- pack: W -> transposed fp16 hi/lo wt[comp][n][k], bias
__global__ __launch_bounds__(256) void pack_kernel(
    const float* __restrict__ Wh, const float* __restrict__ bh,
    const float* __restrict__ Wa, const float* __restrict__ ba,
    const float* __restrict__ Wu, const float* __restrict__ bu,
    const float* __restrict__ Wl_, const float* __restrict__ bl,
    const float* __restrict__ Wf, const float* __restrict__ bf,
    char* __restrict__ wsb) {
  _Float16* wt_h = (_Float16*)(wsb + OFF_WT);
  _Float16* wt_l = wt_h + (size_t)NPAD * KT;
  float* bias = (float*)(wsb + OFF_BIAS);
  __shared__ _Float16 sh[64][128];
  __shared__ _Float16 sl[64][128];
  const int k0 = blockIdx.x * 64;
  const int tid = threadIdx.x;

#pragma unroll
  for (int jj = 0; jj < 32; ++jj) {
    int idx = tid + 256 * jj;
    int kk = idx >> 7, n = idx & 127;
    int k = k0 + kk;
    float w = 0.f;
    if (k < KDIM) {
      if      (n < 28)  w = Wh [k * 28 + n];
      else if (n < 56)  w = Wa [k * 28 + (n - 28)];
      else if (n < 84)  w = Wu [k * 28 + (n - 56)];
      else if (n < 112) w = Wl_[k * 28 + (n - 84)];
      else if (n < 126) w = Wf [k * 14 + (n - 112)];
    }
    _Float16 h = (_Float16)w;
    _Float16 l = (_Float16)((w - (float)h) * 2048.0f);
    sh[kk][n] = h;
    sl[kk][n] = l;
  }
  if (blockIdx.x == 0 && tid < NPAD) {
    int n = tid;
    float v = 0.f;
    if      (n < 28)  v = bh[n];
    else if (n < 56)  v = ba[n - 28];
    else if (n < 84)  v = bu[n - 56];
    else if (n < 112) v = bl[n - 84];
    else if (n < 126) v = bf[n - 112];
    bias[n] = v;
  }
  __syncthreads();
  const int n = tid >> 1;
  const int kc = (tid & 1) * 32;
  size_t ob = (size_t)n * KT + k0 + kc;
#pragma unroll
  for (int c = 0; c < 4; ++c) {
    uint4 qh, ql;
    qh.x = pk16(sh[kc + c * 8 + 0][n], sh[kc + c * 8 + 1][n]);
    qh.y = pk16(sh[kc + c * 8 + 2][n], sh[kc + c * 8 + 3][n]);
    qh.z = pk16(sh[kc + c * 8 + 4][n], sh[kc + c * 8 + 5][n]);
    qh.w = pk16(sh[kc + c * 8 + 6][n], sh[kc + c * 8 + 7][n]);
    ql.x = pk16(sl[kc + c * 8 + 0][n], sl[kc + c * 8 + 1][n]);
    ql.y = pk16(sl[kc + c * 8 + 2][n], sl[kc + c * 8 + 3][n]);
    ql.z = pk16(sl[kc + c * 8 + 4][n], sl[kc + c * 8 + 5][n]);
    ql.w = pk16(sl[kc + c * 8 + 6][n], sl[kc + c * 8 + 7][n]);
    *(uint4*)(wt_h + ob + c * 8) = qh;
    *(uint4*)(wt_l + ob + c * 8) = ql;
  }
}

// ---------------- GEMM: partial[s] = x[:, slice] @ W[slice, :]
// Fully wave-independent: no LDS, no barriers, no asm waits. Each wave owns a
// 32x32 output tile for one K-split. A from global x (float2, 8B-aligned),
// B from packed fp16 wt (L2-resident; split=bid&7 pins slice to one XCD's L2).
__global__ __launch_bounds__(256, 4) void gemm_kernel(const float* __restrict__ x,
                                                      const char* __restrict__ wsb_in,
                                                      char* __restrict__ wsb_out) {
  const _Float16* wt = (const _Float16*)(wsb_in + OFF_WT);
  float* partial = (float*)(wsb_out + OFF_PART);
  const int bid = blockIdx.x;
  const int split = bid & 7;                 // consecutive bids -> XCD round-robin
  const int q = bid >> 3;                    // 0..127
  const int cq = q & 3;                      // col quarter
  const int rg = q >> 2;                     // row group 0..31
  const int tid = threadIdx.x;
  const int lane = tid & 63;
  const int wid = tid >> 6;
  const int row0 = rg * 128 + wid * 32;
  const int col0 = cq * 32;
  const int ks = split * KSLICE;
  const int kh = lane >> 5;
  const int lr = lane & 31;

  const float* xrp = x + (size_t)(row0 + lr) * KDIM + kh * 8;      // lane's row
  const _Float16* bph = wt + (size_t)(col0 + lr) * KT + ks + kh * 8;
  const _Float16* bpl = bph + (size_t)NPAD * KT;

  f32x16 accA = (f32x16)(0.f), accB = (f32x16)(0.f);

#pragma unroll 2
  for (int t = 0; t < NITER; ++t) {
    const int kb = ks + t * BK;
    // ---- B fragments (L2)
    half8 bh2[2], bl2[2];
    bh2[0] = *(const half8*)(bph + t * BK);
    bh2[1] = *(const half8*)(bph + t * BK + 16);
    bl2[0] = *(const half8*)(bpl + t * BK);
    bl2[1] = *(const half8*)(bpl + t * BK + 16);
    // ---- A fragments (global x, 16 floats/lane)
    float f[16];
    if (kb + BK <= KDIM) {
      const float* a0 = xrp + kb;
#pragma unroll
      for (int j = 0; j < 4; ++j) {
        float2 v = *(const float2*)(a0 + 2 * j);
        f[2 * j] = v.x; f[2 * j + 1] = v.y;
      }
#pragma unroll
      for (int j = 0; j < 4; ++j) {
        float2 v = *(const float2*)(a0 + 16 + 2 * j);
        f[8 + 2 * j] = v.x; f[8 + 2 * j + 1] = v.y;
      }
    } else {
#pragma unroll
      for (int i = 0; i < 8; ++i) {
        int k0g = kb + kh * 8 + i;
        f[i]     = (k0g      < KDIM) ? xrp[kb + i]      : 0.f;
        f[8 + i] = (k0g + 16 < KDIM) ? xrp[kb + 16 + i] : 0.f;
      }
    }
    // ---- fp32 -> hi/lo fp16
    half8 ah[2], al[2];
#pragma unroll
    for (int ksub = 0; ksub < 2; ++ksub)
#pragma unroll
      for (int i = 0; i < 8; ++i) {
        float v = f[ksub * 8 + i];
        _Float16 h = (_Float16)v;
        ah[ksub][i] = h;
        al[ksub][i] = (_Float16)((v - (float)h) * 2048.0f);
      }
    // ---- MFMA (same order as prior rounds -> bit-identical)
#pragma unroll
    for (int ksub = 0; ksub < 2; ++ksub) {
      accA = __builtin_amdgcn_mfma_f32_32x32x16_f16(ah[ksub], bh2[ksub], accA, 0, 0, 0);
      accB = __builtin_amdgcn_mfma_f32_32x32x16_f16(al[ksub], bh2[ksub], accB, 0, 0, 0);
      accB = __builtin_amdgcn_mfma_f32_32x32x16_f16(ah[ksub], bl2[ksub], accB, 0, 0, 0);
    }
  }

  float* pb = partial + (size_t)split * BSZ * NPAD;
#pragma unroll
  for (int r = 0; r < 16; ++r) {
    int row = row0 + (r & 3) + 8 * (r >> 2) + 4 * kh;
    pb[(size_t)row * NPAD + col0 + lr] = accA[r] + accB[r] * (1.0f / 2048.0f);
  }
}

// ---------------- fused reduce + epilogue (coalesced via LDS)
__device__ __forceinline__ void axis_mask(const float a[WD], int lo, int hi, float m[WD]) {
  float am[WD];
  float tot = 0.f;
#pragma unroll
  for (int c = 0; c < WD; ++c) { am[c] = (c >= lo) ? a[c] : 0.f; tot += am[c]; }
  float run = 0.f;
  float c1[WD];
#pragma unroll
  for (int c = 0; c < WD; ++c) {
    run += am[c] / tot;
    c1[c] = (run >= 0.3f) ? run : 0.f;
  }
  float tot2 = 0.f;
#pragma unroll
  for (int c = 0; c < WD; ++c) { am[c] = (c < hi) ? a[c] : 0.f; tot2 += am[c]; }
  run = 0.f;
#pragma unroll
  for (int c = 0; c < WD; ++c) {
    run += am[c] / tot2;
    float c2 = 1.f - run;
    c2 = (c2 >= 0.3f) ? c2 : 0.f;
    m[c] = c1[c] * c2;
  }
}

__global__ __launch_bounds__(256) void epi_kernel(const char* __restrict__ wsb,
                                                  const float* __restrict__ keypoint,
                                                  float* __restrict__ out) {
  __shared__ float vlds[64][132];            // pad 4 floats
  const int b0 = blockIdx.x * 64;
  const int tid = threadIdx.x;
  const float4* part4 = (const float4*)(wsb + OFF_PART);
  const float4* bias4 = (const float4*)(wsb + OFF_BIAS);

  // phase 1: coalesced splitK reduce into LDS (order: sp ascending, bias last)
  float4 a[8];
#pragma unroll
  for (int j = 0; j < 8; ++j) {
    int fi = tid * 8 + j;                    // 0..2047 ; r = fi>>5, c4 = fi&31
    a[j] = part4[((size_t)(b0 + (fi >> 5))) * 32 + (fi & 31)];
  }
  for (int sp = 1; sp < SPLITK; ++sp) {
#pragma unroll
    for (int j = 0; j < 8; ++j) {
      int fi = tid * 8 + j;
      float4 p = part4[((size_t)sp * BSZ + b0 + (fi >> 5)) * 32 + (fi & 31)];
      a[j].x += p.x; a[j].y += p.y; a[j].z += p.z; a[j].w += p.w;
    }
  }
#pragma unroll
  for (int j = 0; j < 8; ++j) {
    int fi = tid * 8 + j;
    float4 bb = bias4[fi & 31];
    a[j].x += bb.x; a[j].y += bb.y; a[j].z += bb.z; a[j].w += bb.w;
    *(float4*)&vlds[fi >> 5][(fi & 31) * 4] = a[j];
  }
  __syncthreads();

  // phase 2: per-(sample,family) math
  for (int u = tid; u < 64 * 5; u += 256) {
    int fam = u >> 6;
    int bl = u & 63;
    int b = b0 + bl;
    const int G = (fam == 4) ? 1 : 2;
    const int nk = (fam == 4) ? 2 : 4;
    const float* vv = &vlds[bl][fam * 28];

    int mnx = 7, mxx = -1, mny = 7, mxy = -1;
    for (int i = 0; i < nk; ++i) {
      int kidx = KIDX[fam][i];
      float fx = keypoint[((size_t)b * 17 + kidx) * 2 + 0];
      float fy = keypoint[((size_t)b * 17 + kidx) * 2 + 1];
      int ix = (int)floorf(fx * 7.0f); ix = ix < 6 ? ix : 6;
      int iy = (int)floorf(fy * 7.0f); iy = iy < 6 ? iy : 6;
      mnx = min(mnx, ix); mxx = max(mxx, ix);
      mny = min(mny, iy); mxy = max(mxy, iy);
    }
    int lox = mnx - 1; if (lox < 0) lox = 0;
    int hix = mxx + 1; if (hix > 6) hix = 6;
    int loy = mny - 1; if (loy < 0) loy = 0;
    int hiy = mxy + 1; if (hiy > 6) hiy = 6;

    float xmg[2][WD], ymg[2][WD];
    float mx = 0.f;
#pragma unroll
    for (int g = 0; g < 2; ++g) {
      if (g < G) {
        const float* vg = vv + g * 14;
        float a0[WD], a1[WD];
#pragma unroll
        for (int c = 0; c < WD; ++c) {
          float s0 = vg[c], s1 = vg[c + 7];
          float mM = fmaxf(s0, s1);
          float e0 = expf(s0 - mM), e1 = expf(s1 - mM);
          float sum = e0 + e1;
          a0[c] = expf(e0 / sum);
          a1[c] = expf(e1 / sum);
        }
        axis_mask(a0, lox, hix, xmg[g]);
        axis_mask(a1, loy, hiy, ymg[g]);
        float mx_x = 0.f, mx_y = 0.f;
#pragma unroll
        for (int c = 0; c < WD; ++c) {
          mx_x = fmaxf(mx_x, xmg[g][c]);
          mx_y = fmaxf(mx_y, ymg[g][c]);
        }
        mx = fmaxf(mx, mx_y * mx_x);
      }
    }

    float d = mx + 1e-7f;
    float* op = out + OBASE[fam] + (size_t)b * (G * 49);
#pragma unroll
    for (int g = 0; g < 2; ++g) {
      if (g < G) {
#pragma unroll
        for (int y = 0; y < WD; ++y) {
          float yv = ymg[g][y];
#pragma unroll
          for (int xx = 0; xx < WD; ++xx) {
            op[g * 49 + y * 7 + xx] = (yv * xmg[g][xx]) / d;
          }
        }
      }
    }
  }
}

extern "C" void kernel_launch(void* const* d_in, const int* in_sizes, int n_in,
                              void* d_out, int out_size, void* d_ws, size_t ws_size,
                              hipStream_t stream) {
  const float* x        = (const float*)d_in[0];
  const float* keypoint = (const float*)d_in[1];
  const float* Wh = (const float*)d_in[2];
  const float* bh = (const float*)d_in[3];
  const float* Wa = (const float*)d_in[4];
  const float* ba = (const float*)d_in[5];
  const float* Wu = (const float*)d_in[6];
  const float* bu = (const float*)d_in[7];
  const float* Wl = (const float*)d_in[8];
  const float* bl = (const float*)d_in[9];
  const float* Wf = (const float*)d_in[10];
  const float* bf = (const float*)d_in[11];
  float* out = (float*)d_out;
  char* wsb  = (char*)d_ws;

  hipLaunchKernelGGL(pack_kernel, dim3(KT / 64), dim3(256), 0, stream,
                     Wh, bh, Wa, ba, Wu, bu, Wl, bl, Wf, bf, wsb);
  hipLaunchKernelGGL(gemm_kernel, dim3(32 * 4 * SPLITK), dim3(256), 0, stream,
                     x, wsb, wsb);
  hipLaunchKernelGGL(epi_kernel, dim3(BSZ / 64), dim3(256), 0, stream,
                     wsb, keypoint, out);
}

// Round 9
// 109.254 us; speedup vs baseline: 1.3915x; 1.3915x over previous
//
#include <hip/hip_runtime.h>

typedef _Float16 half8 __attribute__((ext_vector_type(8)));
typedef float f32x4 __attribute__((ext_vector_type(4)));

#define WD 7
#define NPAD 128
#define KDIM 8330
#define KT 8704          // 8 * KSLICE; wt rows zero-padded past 8330
#define BSZ 4096
#define SPLITK 8
#define KSLICE 1088      // 34 * 32
#define NITER 34
#define BM 64
#define BK 32

// ws layout (bytes)
static constexpr size_t OFF_WT   = 0;                              // _Float16[2][128][KT]
static constexpr size_t WT_BYTES = (size_t)2 * NPAD * KT * 2;      // 4,456,448
static constexpr size_t OFF_BIAS = WT_BYTES;                       // 128 floats
static constexpr size_t OFF_PART = OFF_BIAS + 512;                 // [SPLITK][BSZ][NPAD] f32
// total ~21.2 MB

static __device__ const int KIDX[5][4] = {
    {0, 1, 3, 4}, {7, 8, 9, 10}, {5, 6, 11, 12}, {11, 12, 13, 14}, {15, 16, 15, 16}};
static __device__ const unsigned long long OBASE[5] = {0ull, 401408ull, 802816ull, 1204224ull, 1605632ull};

__device__ __forceinline__ unsigned pk16(_Float16 a, _Float16 b) {
  return (unsigned)__builtin_bit_cast(unsigned short, a) |
         ((unsigned)__builtin_bit_cast(unsigned short, b) << 16);
}

__device__ __forceinline__ void gload_lds16(const void* g, void* l) {
  __builtin_amdgcn_global_load_lds((const __attribute__((address_space(1))) unsigned int*)g,
                                   (__attribute__((address_space(3))) unsigned int*)l, 16, 0, 0);
}

// ---------------- pack: W -> transposed fp16 hi/lo wt[comp][n][k], bias
__global__ __launch_bounds__(256) void pack_kernel(
    const float* __restrict__ Wh, const float* __restrict__ bh,
    const float* __restrict__ Wa, const float* __restrict__ ba,
    const float* __restrict__ Wu, const float* __restrict__ bu,
    const float* __restrict__ Wl_, const float* __restrict__ bl,
    const float* __restrict__ Wf, const float* __restrict__ bf,
    char* __restrict__ wsb) {
  _Float16* wt_h = (_Float16*)(wsb + OFF_WT);
  _Float16* wt_l = wt_h + (size_t)NPAD * KT;
  float* bias = (float*)(wsb + OFF_BIAS);
  __shared__ _Float16 sh[64][128];
  __shared__ _Float16 sl[64][128];
  const int k0 = blockIdx.x * 64;
  const int tid = threadIdx.x;

#pragma unroll
  for (int jj = 0; jj < 32; ++jj) {
    int idx = tid + 256 * jj;
    int kk = idx >> 7, n = idx & 127;
    int k = k0 + kk;
    float w = 0.f;
    if (k < KDIM) {
      if      (n < 28)  w = Wh [k * 28 + n];
      else if (n < 56)  w = Wa [k * 28 + (n - 28)];
      else if (n < 84)  w = Wu [k * 28 + (n - 56)];
      else if (n < 112) w = Wl_[k * 28 + (n - 84)];
      else if (n < 126) w = Wf [k * 14 + (n - 112)];
    }
    _Float16 h = (_Float16)w;
    _Float16 l = (_Float16)((w - (float)h) * 2048.0f);
    sh[kk][n] = h;
    sl[kk][n] = l;
  }
  if (blockIdx.x == 0 && tid < NPAD) {
    int n = tid;
    float v = 0.f;
    if      (n < 28)  v = bh[n];
    else if (n < 56)  v = ba[n - 28];
    else if (n < 84)  v = bu[n - 56];
    else if (n < 112) v = bl[n - 84];
    else if (n < 126) v = bf[n - 112];
    bias[n] = v;
  }
  __syncthreads();
  const int n = tid >> 1;
  const int kc = (tid & 1) * 32;
  size_t ob = (size_t)n * KT + k0 + kc;
#pragma unroll
  for (int c = 0; c < 4; ++c) {
    uint4 qh, ql;
    qh.x = pk16(sh[kc + c * 8 + 0][n], sh[kc + c * 8 + 1][n]);
    qh.y = pk16(sh[kc + c * 8 + 2][n], sh[kc + c * 8 + 3][n]);
    qh.z = pk16(sh[kc + c * 8 + 4][n], sh[kc + c * 8 + 5][n]);
    qh.w = pk16(sh[kc + c * 8 + 6][n], sh[kc + c * 8 + 7][n]);
    ql.x = pk16(sl[kc + c * 8 + 0][n], sl[kc + c * 8 + 1][n]);
    ql.y = pk16(sl[kc + c * 8 + 2][n], sl[kc + c * 8 + 3][n]);
    ql.z = pk16(sl[kc + c * 8 + 4][n], sl[kc + c * 8 + 5][n]);
    ql.w = pk16(sl[kc + c * 8 + 6][n], sl[kc + c * 8 + 7][n]);
    *(uint4*)(wt_h + ob + c * 8) = qh;
    *(uint4*)(wt_l + ob + c * 8) = ql;
  }
}

// ---------------- GEMM: partial[s] = x[:, slice] @ W[slice, :]
// m97-style: both operands via LDS, coalesced staging, one barrier/iter,
// stage(t+1) issued before compute(t), counted auto-waits.
__global__ __launch_bounds__(256) void gemm_kernel(const float* __restrict__ x,
                                                   char* __restrict__ wsb) {
  const _Float16* wt = (const _Float16*)(wsb + OFF_WT);
  float* partial = (float*)(wsb + OFF_PART);
  const int bid = blockIdx.x;
  const int split = bid & 7;                 // XCD round-robin pins W slice to L2
  const int row0 = (bid >> 3) * BM;
  const int ks = split * KSLICE;

  // A: [buf][comp][slot4][row64][8h] = 16 KB ; W: [buf][comp][slot4][col128][8h] = 32 KB
  __shared__ _Float16 alds[2][2][4][64][8];
  __shared__ _Float16 wlds[2][2][4][128][8];

  const int tid = threadIdx.x;
  const int lane = tid & 63;
  const int wid = tid >> 6;
  const int wm = wid & 1;                    // row half (32)
  const int wn = wid >> 1;                   // col half (64)

  // ---- x load mapping: thread -> (row = tid>>2, slot = tid&3, 8 consecutive k)
  const int xrow = tid >> 2;
  const int xslot = tid & 3;
  const float* xrp = x + (size_t)(row0 + xrow) * KDIM;
  float xv[8];
  auto loadX = [&](int t) {
    const int k0 = ks + t * BK + xslot * 8;
#pragma unroll
    for (int j = 0; j < 4; ++j) {
      int k = k0 + 2 * j;
      if (k + 2 <= KDIM) {
        float2 v = *(const float2*)(xrp + k);
        xv[2 * j] = v.x; xv[2 * j + 1] = v.y;
      } else {
        xv[2 * j]     = (k     < KDIM) ? xrp[k]     : 0.f;
        xv[2 * j + 1] = (k + 1 < KDIM) ? xrp[k + 1] : 0.f;
      }
    }
  };
  auto writeX = [&](int buf) {
    half8 hi, lo;
#pragma unroll
    for (int i = 0; i < 8; ++i) {
      float v = xv[i];
      _Float16 h = (_Float16)v;
      hi[i] = h;
      lo[i] = (_Float16)((v - (float)h) * 2048.0f);
    }
    *(half8*)&alds[buf][0][xslot][xrow][0] = hi;
    *(half8*)&alds[buf][1][xslot][xrow][0] = lo;
  };

  // ---- W staging: 1024 16B chunks -> [comp][slot][col], lane-contiguous dest
  auto stageW = [&](int buf, int t) {
    const int kbase = ks + t * BK;
#pragma unroll
    for (int c = 0; c < 4; ++c) {
      int chunk0 = wid * 256 + c * 64;       // wave-uniform
      int comp = chunk0 >> 9;
      int slot = (chunk0 >> 7) & 3;
      int colb = chunk0 & 127;               // 0 or 64
      const _Float16* src = wt + (size_t)comp * NPAD * KT +
                            (size_t)(colb + lane) * KT + kbase + slot * 8;
      gload_lds16((const void*)src, (void*)&wlds[buf][comp][slot][colb][0]);
    }
  };

  f32x4 accA[2][4], accB[2][4];
#pragma unroll
  for (int mt = 0; mt < 2; ++mt)
#pragma unroll
    for (int nt = 0; nt < 4; ++nt) { accA[mt][nt] = (f32x4)(0.f); accB[mt][nt] = (f32x4)(0.f); }

  const int fr = lane & 15;                  // fragment row/col
  const int fslot = lane >> 4;               // k-slot 0..3

  // ---- prologue: stage tile 0 into buf 0
  loadX(0);
  __builtin_amdgcn_sched_barrier(0);
  stageW(0, 0);
  __builtin_amdgcn_sched_barrier(0);
  writeX(0);
  asm volatile("s_waitcnt vmcnt(0) lgkmcnt(0)" ::: "memory");
  __builtin_amdgcn_sched_barrier(0);
  __builtin_amdgcn_s_barrier();

  for (int t = 0; t < NITER; ++t) {
    const int cur = t & 1;
    const bool hasNext = (t + 1 < NITER);

    // 1) issue x(t+1) global loads (HBM, oldest in queue)
    if (hasNext) loadX(t + 1);
    __builtin_amdgcn_sched_barrier(0);
    // 2) issue W(t+1) DMA (L2 -> LDS alt buffer)
    if (hasNext) stageW(cur ^ 1, t + 1);
    __builtin_amdgcn_sched_barrier(0);

    // 3) fragments of tile t + MFMA
    half8 a_h[2], a_l[2], b_h[4], b_l[4];
#pragma unroll
    for (int mt = 0; mt < 2; ++mt) {
      a_h[mt] = *(const half8*)&alds[cur][0][fslot][wm * 32 + mt * 16 + fr][0];
      a_l[mt] = *(const half8*)&alds[cur][1][fslot][wm * 32 + mt * 16 + fr][0];
    }
#pragma unroll
    for (int nt = 0; nt < 4; ++nt) {
      b_h[nt] = *(const half8*)&wlds[cur][0][fslot][wn * 64 + nt * 16 + fr][0];
      b_l[nt] = *(const half8*)&wlds[cur][1][fslot][wn * 64 + nt * 16 + fr][0];
    }
#pragma unroll
    for (int mt = 0; mt < 2; ++mt)
#pragma unroll
      for (int nt = 0; nt < 4; ++nt) {
        accA[mt][nt] = __builtin_amdgcn_mfma_f32_16x16x32_f16(a_h[mt], b_h[nt], accA[mt][nt], 0, 0, 0);
        accB[mt][nt] = __builtin_amdgcn_mfma_f32_16x16x32_f16(a_l[mt], b_h[nt], accB[mt][nt], 0, 0, 0);
        accB[mt][nt] = __builtin_amdgcn_mfma_f32_16x16x32_f16(a_h[mt], b_l[nt], accB[mt][nt], 0, 0, 0);
      }

    // 4) convert + write A(t+1) (auto counted vmcnt retires only the x loads)
    if (hasNext) writeX(cur ^ 1);

    // 5) drain W(t+1) DMA + LDS ops, one barrier
    asm volatile("s_waitcnt vmcnt(0) lgkmcnt(0)" ::: "memory");
    __builtin_amdgcn_sched_barrier(0);
    __builtin_amdgcn_s_barrier();
  }

  float* pb = partial + (size_t)split * BSZ * NPAD;
#pragma unroll
  for (int mt = 0; mt < 2; ++mt)
#pragma unroll
    for (int nt = 0; nt < 4; ++nt) {
      int col = wn * 64 + nt * 16 + fr;
#pragma unroll
      for (int r = 0; r < 4; ++r) {
        int row = row0 + wm * 32 + mt * 16 + fslot * 4 + r;
        pb[(size_t)row * NPAD + col] = accA[mt][nt][r] + accB[mt][nt][r] * (1.0f / 2048.0f);
      }
    }
}

// ---------------- fused reduce + epilogue (coalesced via LDS)
__device__ __forceinline__ void axis_mask(const float a[WD], int lo, int hi, float m[WD]) {
  float am[WD];
  float tot = 0.f;
#pragma unroll
  for (int c = 0; c < WD; ++c) { am[c] = (c >= lo) ? a[c] : 0.f; tot += am[c]; }
  float run = 0.f;
  float c1[WD];
#pragma unroll
  for (int c = 0; c < WD; ++c) {
    run += am[c] / tot;
    c1[c] = (run >= 0.3f) ? run : 0.f;
  }
  float tot2 = 0.f;
#pragma unroll
  for (int c = 0; c < WD; ++c) { am[c] = (c < hi) ? a[c] : 0.f; tot2 += am[c]; }
  run = 0.f;
#pragma unroll
  for (int c = 0; c < WD; ++c) {
    run += am[c] / tot2;
    float c2 = 1.f - run;
    c2 = (c2 >= 0.3f) ? c2 : 0.f;
    m[c] = c1[c] * c2;
  }
}

__global__ __launch_bounds__(256) void epi_kernel(const char* __restrict__ wsb,
                                                  const float* __restrict__ keypoint,
                                                  float* __restrict__ out) {
  __shared__ float vlds[64][132];            // pad 4 floats
  const int b0 = blockIdx.x * 64;
  const int tid = threadIdx.x;
  const float4* part4 = (const float4*)(wsb + OFF_PART);
  const float4* bias4 = (const float4*)(wsb + OFF_BIAS);

  float4 a[8];
#pragma unroll
  for (int j = 0; j < 8; ++j) {
    int fi = tid * 8 + j;
    a[j] = part4[((size_t)(b0 + (fi >> 5))) * 32 + (fi & 31)];
  }
  for (int sp = 1; sp < SPLITK; ++sp) {
#pragma unroll
    for (int j = 0; j < 8; ++j) {
      int fi = tid * 8 + j;
      float4 p = part4[((size_t)sp * BSZ + b0 + (fi >> 5)) * 32 + (fi & 31)];
      a[j].x += p.x; a[j].y += p.y; a[j].z += p.z; a[j].w += p.w;
    }
  }
#pragma unroll
  for (int j = 0; j < 8; ++j) {
    int fi = tid * 8 + j;
    float4 bb = bias4[fi & 31];
    a[j].x += bb.x; a[j].y += bb.y; a[j].z += bb.z; a[j].w += bb.w;
    *(float4*)&vlds[fi >> 5][(fi & 31) * 4] = a[j];
  }
  __syncthreads();

  for (int u = tid; u < 64 * 5; u += 256) {
    int fam = u >> 6;
    int bl = u & 63;
    int b = b0 + bl;
    const int G = (fam == 4) ? 1 : 2;
    const int nk = (fam == 4) ? 2 : 4;
    const float* vv = &vlds[bl][fam * 28];

    int mnx = 7, mxx = -1, mny = 7, mxy = -1;
    for (int i = 0; i < nk; ++i) {
      int kidx = KIDX[fam][i];
      float fx = keypoint[((size_t)b * 17 + kidx) * 2 + 0];
      float fy = keypoint[((size_t)b * 17 + kidx) * 2 + 1];
      int ix = (int)floorf(fx * 7.0f); ix = ix < 6 ? ix : 6;
      int iy = (int)floorf(fy * 7.0f); iy = iy < 6 ? iy : 6;
      mnx = min(mnx, ix); mxx = max(mxx, ix);
      mny = min(mny, iy); mxy = max(mxy, iy);
    }
    int lox = mnx - 1; if (lox < 0) lox = 0;
    int hix = mxx + 1; if (hix > 6) hix = 6;
    int loy = mny - 1; if (loy < 0) loy = 0;
    int hiy = mxy + 1; if (hiy > 6) hiy = 6;

    float xmg[2][WD], ymg[2][WD];
    float mx = 0.f;
#pragma unroll
    for (int g = 0; g < 2; ++g) {
      if (g < G) {
        const float* vg = vv + g * 14;
        float a0[WD], a1[WD];
#pragma unroll
        for (int c = 0; c < WD; ++c) {
          float s0 = vg[c], s1 = vg[c + 7];
          float mM = fmaxf(s0, s1);
          float e0 = expf(s0 - mM), e1 = expf(s1 - mM);
          float sum = e0 + e1;
          a0[c] = expf(e0 / sum);
          a1[c] = expf(e1 / sum);
        }
        axis_mask(a0, lox, hix, xmg[g]);
        axis_mask(a1, loy, hiy, ymg[g]);
        float mx_x = 0.f, mx_y = 0.f;
#pragma unroll
        for (int c = 0; c < WD; ++c) {
          mx_x = fmaxf(mx_x, xmg[g][c]);
          mx_y = fmaxf(mx_y, ymg[g][c]);
        }
        mx = fmaxf(mx, mx_y * mx_x);
      }
    }

    float d = mx + 1e-7f;
    float* op = out + OBASE[fam] + (size_t)b * (G * 49);
#pragma unroll
    for (int g = 0; g < 2; ++g) {
      if (g < G) {
#pragma unroll
        for (int y = 0; y < WD; ++y) {
          float yv = ymg[g][y];
#pragma unroll
          for (int xx = 0; xx < WD; ++xx) {
            op[g * 49 + y * 7 + xx] = (yv * xmg[g][xx]) / d;
          }
        }
      }
    }
  }
}

extern "C" void kernel_launch(void* const* d_in, const int* in_sizes, int n_in,
                              void* d_out, int out_size, void* d_ws, size_t ws_size,
                              hipStream_t stream) {
  const float* x        = (const float*)d_in[0];
  const float* keypoint = (const float*)d_in[1];
  const float* Wh = (const float*)d_in[2];
  const float* bh = (const float*)d_in[3];
  const float* Wa = (const float*)d_in[4];
  const float* ba = (const float*)d_in[5];
  const float* Wu = (const float*)d_in[6];
  const float* bu = (const float*)d_in[7];
  const float* Wl = (const float*)d_in[8];
  const float* bl = (const float*)d_in[9];
  const float* Wf = (const float*)d_in[10];
  const float* bf = (const float*)d_in[11];
  float* out = (float*)d_out;
  char* wsb  = (char*)d_ws;

  hipLaunchKernelGGL(pack_kernel, dim3(KT / 64), dim3(256), 0, stream,
                     Wh, bh, Wa, ba, Wu, bu, Wl, bl, Wf, bf, wsb);
  hipLaunchKernelGGL(gemm_kernel, dim3((BSZ / BM) * SPLITK), dim3(256), 0, stream, x, wsb);
  hipLaunchKernelGGL(epi_kernel, dim3(BSZ / 64), dim3(256), 0, stream,
                     wsb, keypoint, out);
}

// Round 10
// 91.965 us; speedup vs baseline: 1.6531x; 1.1880x over previous
//
#include <hip/hip_runtime.h>

typedef _Float16 half8 __attribute__((ext_vector_type(8)));
typedef float f32x4 __attribute__((ext_vector_type(4)));

#define WD 7
#define NPAD 128
#define KDIM 8330
#define KT 8704          // 8 * KSLICE; wt rows zero-padded past 8330
#define BSZ 4096
#define SPLITK 8
#define KSLICE 1088      // 34 * 32
#define NITER 34
#define BM 64
#define BK 32

// ws layout (bytes)
static constexpr size_t OFF_WT   = 0;                              // _Float16[2][128][KT]
static constexpr size_t WT_BYTES = (size_t)2 * NPAD * KT * 2;      // 4,456,448
static constexpr size_t OFF_BIAS = WT_BYTES;                       // 128 floats
static constexpr size_t OFF_PART = OFF_BIAS + 512;                 // [SPLITK][BSZ][NPAD] f32
// total ~21.2 MB

static __device__ const int KIDX[5][4] = {
    {0, 1, 3, 4}, {7, 8, 9, 10}, {5, 6, 11, 12}, {11, 12, 13, 14}, {15, 16, 15, 16}};
static __device__ const unsigned long long OBASE[5] = {0ull, 401408ull, 802816ull, 1204224ull, 1605632ull};

__device__ __forceinline__ unsigned pk16(_Float16 a, _Float16 b) {
  return (unsigned)__builtin_bit_cast(unsigned short, a) |
         ((unsigned)__builtin_bit_cast(unsigned short, b) << 16);
}

__device__ __forceinline__ void gload_lds16(const void* g, void* l) {
  __builtin_amdgcn_global_load_lds((const __attribute__((address_space(1))) unsigned int*)g,
                                   (__attribute__((address_space(3))) unsigned int*)l, 16, 0, 0);
}

// ---------------- pack: W -> transposed fp16 hi/lo wt[comp][n][k], bias
__global__ __launch_bounds__(256) void pack_kernel(
    const float* __restrict__ Wh, const float* __restrict__ bh,
    const float* __restrict__ Wa, const float* __restrict__ ba,
    const float* __restrict__ Wu, const float* __restrict__ bu,
    const float* __restrict__ Wl_, const float* __restrict__ bl,
    const float* __restrict__ Wf, const float* __restrict__ bf,
    char* __restrict__ wsb) {
  _Float16* wt_h = (_Float16*)(wsb + OFF_WT);
  _Float16* wt_l = wt_h + (size_t)NPAD * KT;
  float* bias = (float*)(wsb + OFF_BIAS);
  __shared__ _Float16 sh[64][128];
  __shared__ _Float16 sl[64][128];
  const int k0 = blockIdx.x * 64;
  const int tid = threadIdx.x;

#pragma unroll
  for (int jj = 0; jj < 32; ++jj) {
    int idx = tid + 256 * jj;
    int kk = idx >> 7, n = idx & 127;
    int k = k0 + kk;
    float w = 0.f;
    if (k < KDIM) {
      if      (n < 28)  w = Wh [k * 28 + n];
      else if (n < 56)  w = Wa [k * 28 + (n - 28)];
      else if (n < 84)  w = Wu [k * 28 + (n - 56)];
      else if (n < 112) w = Wl_[k * 28 + (n - 84)];
      else if (n < 126) w = Wf [k * 14 + (n - 112)];
    }
    _Float16 h = (_Float16)w;
    _Float16 l = (_Float16)((w - (float)h) * 2048.0f);
    sh[kk][n] = h;
    sl[kk][n] = l;
  }
  if (blockIdx.x == 0 && tid < NPAD) {
    int n = tid;
    float v = 0.f;
    if      (n < 28)  v = bh[n];
    else if (n < 56)  v = ba[n - 28];
    else if (n < 84)  v = bu[n - 56];
    else if (n < 112) v = bl[n - 84];
    else if (n < 126) v = bf[n - 112];
    bias[n] = v;
  }
  __syncthreads();
  const int n = tid >> 1;
  const int kc = (tid & 1) * 32;
  size_t ob = (size_t)n * KT + k0 + kc;
#pragma unroll
  for (int c = 0; c < 4; ++c) {
    uint4 qh, ql;
    qh.x = pk16(sh[kc + c * 8 + 0][n], sh[kc + c * 8 + 1][n]);
    qh.y = pk16(sh[kc + c * 8 + 2][n], sh[kc + c * 8 + 3][n]);
    qh.z = pk16(sh[kc + c * 8 + 4][n], sh[kc + c * 8 + 5][n]);
    qh.w = pk16(sh[kc + c * 8 + 6][n], sh[kc + c * 8 + 7][n]);
    ql.x = pk16(sl[kc + c * 8 + 0][n], sl[kc + c * 8 + 1][n]);
    ql.y = pk16(sl[kc + c * 8 + 2][n], sl[kc + c * 8 + 3][n]);
    ql.z = pk16(sl[kc + c * 8 + 4][n], sl[kc + c * 8 + 5][n]);
    ql.w = pk16(sl[kc + c * 8 + 6][n], sl[kc + c * 8 + 7][n]);
    *(uint4*)(wt_h + ob + c * 8) = qh;
    *(uint4*)(wt_l + ob + c * 8) = ql;
  }
}

// ---------------- GEMM: partial[s] = x[:, slice] @ W[slice, :]
// Coalesced staging: W chunks are 64B k-contiguous (1 line/col), x lanes map
// 4 rows x 128B per instr. Linear 64B-row LDS + XOR slot swizzle (<=2-way).
__global__ __launch_bounds__(256) void gemm_kernel(const float* __restrict__ x,
                                                   char* __restrict__ wsb) {
  const _Float16* wt = (const _Float16*)(wsb + OFF_WT);
  float* partial = (float*)(wsb + OFF_PART);
  const int bid = blockIdx.x;
  const int split = bid & 7;                 // XCD round-robin pins W slice to L2
  const int row0 = (bid >> 3) * BM;
  const int ks = split * KSLICE;

  // [buf][comp][row/col][32 halves = 64B], slots XOR-swizzled
  __shared__ _Float16 alds[2][2][64][32];    // 16 KB
  __shared__ _Float16 wlds[2][2][128][32];   // 32 KB

  const int tid = threadIdx.x;
  const int lane = tid & 63;
  const int wid = tid >> 6;
  const int wm = wid & 1;                    // row half (32)
  const int wn = wid >> 1;                   // col half (64)

  // ---- x: 4 coalesced float2 per thread; instr j covers rows (wid*16+4j..+3)
  const int xinrow = lane & 15;              // 16 lanes per row
  const int xc0 = xinrow * 2;                // float col pair in BK slice
  float2 xv[4];
  auto loadX = [&](int t) {
    const int kb = ks + t * BK + xc0;
#pragma unroll
    for (int j = 0; j < 4; ++j) {
      int row = wid * 16 + 4 * j + (lane >> 4);
      const float* p = x + (size_t)(row0 + row) * KDIM + kb;
      if (kb + 2 <= KDIM) {
        xv[j] = *(const float2*)p;
      } else {
        xv[j].x = (kb     < KDIM) ? p[0] : 0.f;
        xv[j].y = (kb + 1 < KDIM) ? p[1] : 0.f;
      }
    }
  };
  auto writeX = [&](int buf) {
    const int slot0 = xinrow >> 2;
    const int off = xinrow & 3;
#pragma unroll
    for (int j = 0; j < 4; ++j) {
      int row = wid * 16 + 4 * j + (lane >> 4);
      int slot = slot0 ^ ((row >> 1) & 3);
      _Float16 h0 = (_Float16)xv[j].x, h1 = (_Float16)xv[j].y;
      unsigned hi = pk16(h0, h1);
      unsigned lo = pk16((_Float16)((xv[j].x - (float)h0) * 2048.0f),
                         (_Float16)((xv[j].y - (float)h1) * 2048.0f));
      *(unsigned*)((char*)&alds[buf][0][row][0] + slot * 16 + off * 4) = hi;
      *(unsigned*)((char*)&alds[buf][1][row][0] + slot * 16 + off * 4) = lo;
    }
  };

  // ---- W staging: chunk = 16 cols x 64B (1 line per col); src slot pre-swizzled
  auto stageW = [&](int buf, int t) {
    const int kb = ks + t * BK;
    const int col_l = lane >> 2;             // 0..15
    const int s = lane & 3;                  // LDS slot this lane fills
#pragma unroll
    for (int c = 0; c < 4; ++c) {
      int chunk = wid * 4 + c;               // 0..15 (wave-uniform)
      int comp = chunk >> 3;
      int colb = (chunk & 7) * 16;
      int col = colb + col_l;
      int ksw = s ^ ((col >> 1) & 3);        // global k-slot feeding LDS slot s
      const _Float16* src = wt + (size_t)comp * NPAD * KT + (size_t)col * KT + kb + ksw * 8;
      gload_lds16((const void*)src, (void*)((char*)&wlds[buf][comp][colb][0] + lane * 16));
    }
  };

  f32x4 accA[2][4], accB[2][4];
#pragma unroll
  for (int mt = 0; mt < 2; ++mt)
#pragma unroll
    for (int nt = 0; nt < 4; ++nt) { accA[mt][nt] = (f32x4)(0.f); accB[mt][nt] = (f32x4)(0.f); }

  const int fr = lane & 15;                  // fragment row/col
  const int fslot = lane >> 4;               // k-slot 0..3
  const int swz = (fslot ^ ((fr >> 1) & 3)) * 16;  // swizzled slot byte offset

  // ---- prologue
  loadX(0);
  __builtin_amdgcn_sched_barrier(0);
  stageW(0, 0);
  __builtin_amdgcn_sched_barrier(0);
  writeX(0);
  asm volatile("s_waitcnt vmcnt(0) lgkmcnt(0)" ::: "memory");
  __builtin_amdgcn_sched_barrier(0);
  __builtin_amdgcn_s_barrier();

  for (int t = 0; t < NITER; ++t) {
    const int cur = t & 1;
    const bool hasNext = (t + 1 < NITER);

    // 1) issue x(t+1) loads (HBM/L3, oldest in queue)
    if (hasNext) loadX(t + 1);
    __builtin_amdgcn_sched_barrier(0);
    // 2) issue W(t+1) DMA (L2 -> alt LDS buffer)
    if (hasNext) stageW(cur ^ 1, t + 1);
    __builtin_amdgcn_sched_barrier(0);

    // 3) fragments of tile t + MFMA
    half8 a_h[2], a_l[2], b_h[4], b_l[4];
#pragma unroll
    for (int mt = 0; mt < 2; ++mt) {
      int row = wm * 32 + mt * 16 + fr;
      a_h[mt] = *(const half8*)((const char*)&alds[cur][0][row][0] + swz);
      a_l[mt] = *(const half8*)((const char*)&alds[cur][1][row][0] + swz);
    }
#pragma unroll
    for (int nt = 0; nt < 4; ++nt) {
      int col = wn * 64 + nt * 16 + fr;
      b_h[nt] = *(const half8*)((const char*)&wlds[cur][0][col][0] + swz);
      b_l[nt] = *(const half8*)((const char*)&wlds[cur][1][col][0] + swz);
    }
#pragma unroll
    for (int mt = 0; mt < 2; ++mt)
#pragma unroll
      for (int nt = 0; nt < 4; ++nt) {
        accA[mt][nt] = __builtin_amdgcn_mfma_f32_16x16x32_f16(a_h[mt], b_h[nt], accA[mt][nt], 0, 0, 0);
        accB[mt][nt] = __builtin_amdgcn_mfma_f32_16x16x32_f16(a_l[mt], b_h[nt], accB[mt][nt], 0, 0, 0);
        accB[mt][nt] = __builtin_amdgcn_mfma_f32_16x16x32_f16(a_h[mt], b_l[nt], accB[mt][nt], 0, 0, 0);
      }

    // 4) convert + ds_write x(t+1) (auto counted vmcnt retires only x loads)
    if (hasNext) writeX(cur ^ 1);

    // 5) drain W(t+1) DMA + LDS, one barrier
    asm volatile("s_waitcnt vmcnt(0) lgkmcnt(0)" ::: "memory");
    __builtin_amdgcn_sched_barrier(0);
    __builtin_amdgcn_s_barrier();
  }

  float* pb = partial + (size_t)split * BSZ * NPAD;
#pragma unroll
  for (int mt = 0; mt < 2; ++mt)
#pragma unroll
    for (int nt = 0; nt < 4; ++nt) {
      int col = wn * 64 + nt * 16 + fr;
#pragma unroll
      for (int r = 0; r < 4; ++r) {
        int row = row0 + wm * 32 + mt * 16 + fslot * 4 + r;
        pb[(size_t)row * NPAD + col] = accA[mt][nt][r] + accB[mt][nt][r] * (1.0f / 2048.0f);
      }
    }
}

// ---------------- fused reduce + epilogue (coalesced via LDS)
__device__ __forceinline__ void axis_mask(const float a[WD], int lo, int hi, float m[WD]) {
  float am[WD];
  float tot = 0.f;
#pragma unroll
  for (int c = 0; c < WD; ++c) { am[c] = (c >= lo) ? a[c] : 0.f; tot += am[c]; }
  float run = 0.f;
  float c1[WD];
#pragma unroll
  for (int c = 0; c < WD; ++c) {
    run += am[c] / tot;
    c1[c] = (run >= 0.3f) ? run : 0.f;
  }
  float tot2 = 0.f;
#pragma unroll
  for (int c = 0; c < WD; ++c) { am[c] = (c < hi) ? a[c] : 0.f; tot2 += am[c]; }
  run = 0.f;
#pragma unroll
  for (int c = 0; c < WD; ++c) {
    run += am[c] / tot2;
    float c2 = 1.f - run;
    c2 = (c2 >= 0.3f) ? c2 : 0.f;
    m[c] = c1[c] * c2;
  }
}

__global__ __launch_bounds__(256) void epi_kernel(const char* __restrict__ wsb,
                                                  const float* __restrict__ keypoint,
                                                  float* __restrict__ out) {
  __shared__ float vlds[64][132];
  const int b0 = blockIdx.x * 64;
  const int tid = threadIdx.x;
  const float4* part4 = (const float4*)(wsb + OFF_PART);
  const float4* bias4 = (const float4*)(wsb + OFF_BIAS);

  float4 a[8];
#pragma unroll
  for (int j = 0; j < 8; ++j) {
    int fi = tid * 8 + j;
    a[j] = part4[((size_t)(b0 + (fi >> 5))) * 32 + (fi & 31)];
  }
  for (int sp = 1; sp < SPLITK; ++sp) {
#pragma unroll
    for (int j = 0; j < 8; ++j) {
      int fi = tid * 8 + j;
      float4 p = part4[((size_t)sp * BSZ + b0 + (fi >> 5)) * 32 + (fi & 31)];
      a[j].x += p.x; a[j].y += p.y; a[j].z += p.z; a[j].w += p.w;
    }
  }
#pragma unroll
  for (int j = 0; j < 8; ++j) {
    int fi = tid * 8 + j;
    float4 bb = bias4[fi & 31];
    a[j].x += bb.x; a[j].y += bb.y; a[j].z += bb.z; a[j].w += bb.w;
    *(float4*)&vlds[fi >> 5][(fi & 31) * 4] = a[j];
  }
  __syncthreads();

  for (int u = tid; u < 64 * 5; u += 256) {
    int fam = u >> 6;
    int bl = u & 63;
    int b = b0 + bl;
    const int G = (fam == 4) ? 1 : 2;
    const int nk = (fam == 4) ? 2 : 4;
    const float* vv = &vlds[bl][fam * 28];

    int mnx = 7, mxx = -1, mny = 7, mxy = -1;
    for (int i = 0; i < nk; ++i) {
      int kidx = KIDX[fam][i];
      float fx = keypoint[((size_t)b * 17 + kidx) * 2 + 0];
      float fy = keypoint[((size_t)b * 17 + kidx) * 2 + 1];
      int ix = (int)floorf(fx * 7.0f); ix = ix < 6 ? ix : 6;
      int iy = (int)floorf(fy * 7.0f); iy = iy < 6 ? iy : 6;
      mnx = min(mnx, ix); mxx = max(mxx, ix);
      mny = min(mny, iy); mxy = max(mxy, iy);
    }
    int lox = mnx - 1; if (lox < 0) lox = 0;
    int hix = mxx + 1; if (hix > 6) hix = 6;
    int loy = mny - 1; if (loy < 0) loy = 0;
    int hiy = mxy + 1; if (hiy > 6) hiy = 6;

    float xmg[2][WD], ymg[2][WD];
    float mx = 0.f;
#pragma unroll
    for (int g = 0; g < 2; ++g) {
      if (g < G) {
        const float* vg = vv + g * 14;
        float a0[WD], a1[WD];
#pragma unroll
        for (int c = 0; c < WD; ++c) {
          float s0 = vg[c], s1 = vg[c + 7];
          float mM = fmaxf(s0, s1);
          float e0 = expf(s0 - mM), e1 = expf(s1 - mM);
          float sum = e0 + e1;
          a0[c] = expf(e0 / sum);
          a1[c] = expf(e1 / sum);
        }
        axis_mask(a0, lox, hix, xmg[g]);
        axis_mask(a1, loy, hiy, ymg[g]);
        float mx_x = 0.f, mx_y = 0.f;
#pragma unroll
        for (int c = 0; c < WD; ++c) {
          mx_x = fmaxf(mx_x, xmg[g][c]);
          mx_y = fmaxf(mx_y, ymg[g][c]);
        }
        mx = fmaxf(mx, mx_y * mx_x);
      }
    }

    float d = mx + 1e-7f;
    float* op = out + OBASE[fam] + (size_t)b * (G * 49);
#pragma unroll
    for (int g = 0; g < 2; ++g) {
      if (g < G) {
#pragma unroll
        for (int y = 0; y < WD; ++y) {
          float yv = ymg[g][y];
#pragma unroll
          for (int xx = 0; xx < WD; ++xx) {
            op[g * 49 + y * 7 + xx] = (yv * xmg[g][xx]) / d;
          }
        }
      }
    }
  }
}

extern "C" void kernel_launch(void* const* d_in, const int* in_sizes, int n_in,
                              void* d_out, int out_size, void* d_ws, size_t ws_size,
                              hipStream_t stream) {
  const float* x        = (const float*)d_in[0];
  const float* keypoint = (const float*)d_in[1];
  const float* Wh = (const float*)d_in[2];
  const float* bh = (const float*)d_in[3];
  const float* Wa = (const float*)d_in[4];
  const float* ba = (const float*)d_in[5];
  const float* Wu = (const float*)d_in[6];
  const float* bu = (const float*)d_in[7];
  const float* Wl = (const float*)d_in[8];
  const float* bl = (const float*)d_in[9];
  const float* Wf = (const float*)d_in[10];
  const float* bf = (const float*)d_in[11];
  float* out = (float*)d_out;
  char* wsb  = (char*)d_ws;

  hipLaunchKernelGGL(pack_kernel, dim3(KT / 64), dim3(256), 0, stream,
                     Wh, bh, Wa, ba, Wu, bu, Wl, bl, Wf, bf, wsb);
  hipLaunchKernelGGL(gemm_kernel, dim3((BSZ / BM) * SPLITK), dim3(256), 0, stream, x, wsb);
  hipLaunchKernelGGL(epi_kernel, dim3(BSZ / 64), dim3(256), 0, stream,
                     wsb, keypoint, out);
}